// Round 15
// baseline (259.176 us; speedup 1.0000x reference)
//
#include <hip/hip_runtime.h>
#include <math.h>

#define NG   16
#define HID  256
#define TPTS 2048                    // table intervals; TPTS+1 entries in d_ws
#define GRID3 2048                   // sweep blocks (8192 waves, co-resident)

typedef float f32x4 __attribute__((ext_vector_type(4)));

constexpr size_t BT      = 32ull * 2048ull;            // 65536 rows
constexpr size_t TOK_OFF = BT * HID;
constexpr size_t WT_OFF  = TOK_OFF + BT * NG * HID;
constexpr size_t NCHUNK  = BT * NG;                    // 1,048,576 1KB chunks
constexpr float  ZLO = -10.0f, ZHI = 10.0f;
constexpr float  ZSTEP  = (ZHI - ZLO) / TPTS;
constexpr float  ZSCALE = TPTS / (ZHI - ZLO);

__device__ __forceinline__ float rln(float v, int l) {  // const-lane -> SGPR
    return __int_as_float(__builtin_amdgcn_readlane(__float_as_int(v), l));
}

// ---- kernel 1: tabulate F(z) = sum_h tanh(z*w_gp[h]+b_gp[h])*w_sp[h] + b_sp
__global__ __launch_bounds__(256) void build_table(
    const float* __restrict__ w_gp, const float* __restrict__ b_gp,
    const float* __restrict__ w_sp, const float* __restrict__ b_sp,
    float* __restrict__ tbl)
{
    const int i = blockIdx.x;              // 0..TPTS
    const int h = threadIdx.x;
    const float z = ZLO + (float)i * ZSTEP;
    float v = tanhf(fmaf(z, w_gp[h], b_gp[h])) * w_sp[h];
    v += __shfl_xor(v, 1, 64);
    v += __shfl_xor(v, 2, 64);
    v += __shfl_xor(v, 4, 64);
    v += __shfl_xor(v, 8, 64);
    v += __shfl_xor(v, 16, 64);
    v += __shfl_xor(v, 32, 64);
    __shared__ float sred[4];
    if ((h & 63) == 0) sred[h >> 6] = v;
    __syncthreads();
    if (h == 0) tbl[i] = sred[0] + sred[1] + sred[2] + sred[3] + b_sp[0];
}

// ---- kernel 2 (exact R9): gv + scores + softmax + visit + weights ----
// wave = 4 rows; lane = (row j = lane>>4, group g = lane&15)
__global__ __launch_bounds__(256) void compute_kernel(
    const float*  __restrict__ x,      // (BT,64)
    const f32x4*  __restrict__ w_gp4,  // (64) float4
    const f32x4*  __restrict__ b_gp4,
    const float*  __restrict__ tbl,    // (TPTS+1)
    float* __restrict__ gvbuf,         // (BT*NG) out: group means
    float* __restrict__ out)
{
    const int lane = threadIdx.x & 63;
    const int wv   = threadIdx.x >> 6;
    const size_t row0 = ((size_t)blockIdx.x * 4 + wv) * 4;  // 4 rows per wave

    __shared__ float sx[4][4][68];     // per-wave staging (+pad, 16B-aligned)
    {
        const f32x4 xl = ((const f32x4*)x)[row0 * 16 + lane];
        const int r = lane >> 4, c = lane & 15;
        *(f32x4*)&sx[wv][r][c * 4] = xl;       // intra-wave only: no barrier
    }

    const int j   = lane >> 4;         // row within wave
    const int g   = lane & 15;         // group
    const int sub = g & 3;             // segment sizes [1,3,5,7] tiled x4
    const int sz  = 2 * sub + 1;
    const int beg = ((g >> 2) << 4) + sub * sub;   // {0,1,4,9}+16*chunk

    float s = 0.0f;
    #pragma unroll
    for (int i = 0; i < 7; ++i)
        if (i < sz) s += sx[wv][j][beg + i];
    const float gv = s * __builtin_amdgcn_rcpf((float)sz);

    // gv out (plain store; stays L2/L3-resident for the sweep's re-read)
    gvbuf[row0 * NG + lane] = gv;

    // ---- score via table lookup + lerp ----
    float idxf = fminf(fmaxf((gv - ZLO) * ZSCALE, 0.0f), (float)TPTS - 0.001f);
    const int   i0 = (int)idxf;
    const float fr = idxf - (float)i0;
    const float t0 = tbl[i0], t1 = tbl[i0 + 1];
    const float score = fmaf(fr, t1 - t0, t0);

    // ---- softmax across the 16-lane group ----
    float m = score;
    m = fmaxf(m, __shfl_xor(m, 1, 64));
    m = fmaxf(m, __shfl_xor(m, 2, 64));
    m = fmaxf(m, __shfl_xor(m, 4, 64));
    m = fmaxf(m, __shfl_xor(m, 8, 64));
    const float e = __expf(score - m);
    float ssum = e;
    ssum += __shfl_xor(ssum, 1, 64);
    ssum += __shfl_xor(ssum, 2, 64);
    ssum += __shfl_xor(ssum, 4, 64);
    ssum += __shfl_xor(ssum, 8, 64);
    const float w = e / ssum;          // weight for (row j, group g)

    __builtin_nontemporal_store(w, out + WT_OFF + row0 * NG + lane);

    // ---- dot_j = sum_g wt_g*gv_g ; visit = dot*w_gp + b_gp (exact) ----
    float d = w * gv;
    d += __shfl_xor(d, 1, 64);
    d += __shfl_xor(d, 2, 64);
    d += __shfl_xor(d, 4, 64);
    d += __shfl_xor(d, 8, 64);

    const f32x4 wg = w_gp4[lane];
    const f32x4 bg = b_gp4[lane];
    #pragma unroll
    for (int jj = 0; jj < 4; ++jj) {
        const float dj = rln(d, jj * 16);
        f32x4 vis;
        vis.x = fmaf(dj, wg.x, bg.x);
        vis.y = fmaf(dj, wg.y, bg.y);
        vis.z = fmaf(dj, wg.z, bg.z);
        vis.w = fmaf(dj, wg.w, bg.w);
        __builtin_nontemporal_store(vis,
            (f32x4*)(out + (row0 + jj) * HID + 4 * lane));
    }
}

// ---- kernel 3: batched-wait token sweep. Same chunk mapping as R9
// (chunk = c0 + k*NW, dense device front), but gv loads are batched 8-ahead
// into registers so the 8 FMA+NT-stores of a batch issue back-to-back with
// NO intervening s_waitcnt -> up to 8 outstanding stores per wave (~64 MB
// device-wide queue depth, the memset regime) instead of ~1 (vmcnt retires
// in issue order; per-iter prefetch waits were draining each store).
__global__ __launch_bounds__(256) void token_sweep(
    const float*  __restrict__ gvbuf,  // (BT*NG)
    const f32x4*  __restrict__ w_gp4,
    const f32x4*  __restrict__ b_gp4,
    float* __restrict__ out)
{
    const int lane = threadIdx.x & 63;
    const int wv   = threadIdx.x >> 6;
    const f32x4 wg = w_gp4[lane];
    const f32x4 bg = b_gp4[lane];
    constexpr size_t NW    = (size_t)GRID3 * 4;          // 8192 waves
    constexpr int    NITER = (int)(NCHUNK / NW);         // 128 (exact)
    constexpr int    B     = 8;                          // batch size
    constexpr int    NBAT  = NITER / B;                  // 16 (exact)

    const size_t c0 = (size_t)blockIdx.x * 4 + wv;
    float* __restrict__ tok = out + TOK_OFF + 4 * lane;

    float cur[B];
    #pragma unroll
    for (int i = 0; i < B; ++i) cur[i] = gvbuf[c0 + (size_t)i * NW];

    #pragma unroll 1
    for (int j = 0; j < NBAT; ++j) {
        float nx[B];
        if (j + 1 < NBAT) {            // issue next batch's loads FIRST:
            #pragma unroll             // waiting on them later never drains
            for (int i = 0; i < B; ++i)//  this batch's stores (issue order)
                nx[i] = gvbuf[c0 + (size_t)((j + 1) * B + i) * NW];
        }
        #pragma unroll
        for (int i = 0; i < B; ++i) {  // 8 stores, no waits in between
            const float v = cur[i];
            f32x4 t;
            t.x = fmaf(v, wg.x, bg.x);
            t.y = fmaf(v, wg.y, bg.y);
            t.z = fmaf(v, wg.z, bg.z);
            t.w = fmaf(v, wg.w, bg.w);
            const size_t c = c0 + (size_t)(j * B + i) * NW;
            __builtin_nontemporal_store(t, (f32x4*)(tok + c * HID));
        }
        #pragma unroll
        for (int i = 0; i < B; ++i) cur[i] = nx[i];
    }
}

extern "C" void kernel_launch(void* const* d_in, const int* in_sizes, int n_in,
                              void* d_out, int out_size, void* d_ws, size_t ws_size,
                              hipStream_t stream) {
    (void)in_sizes; (void)n_in; (void)out_size; (void)ws_size;
    const float* x    = (const float*)d_in[0];
    const float* w_gp = (const float*)d_in[1];
    const float* b_gp = (const float*)d_in[2];
    const float* w_sp = (const float*)d_in[3];
    const float* b_sp = (const float*)d_in[4];
    float* out = (float*)d_out;
    float* tbl   = (float*)d_ws;                          // 8196 B
    float* gvbuf = (float*)((char*)d_ws + 16384);         // 4 MB (proven in R9)

    build_table<<<dim3(TPTS + 1), dim3(256), 0, stream>>>(
        w_gp, b_gp, w_sp, b_sp, tbl);

    compute_kernel<<<dim3((unsigned)(BT / 16)), dim3(256), 0, stream>>>(
        x, (const f32x4*)w_gp, (const f32x4*)b_gp, tbl, gvbuf, out);

    token_sweep<<<dim3(GRID3), dim3(256), 0, stream>>>(
        gvbuf, (const f32x4*)w_gp, (const f32x4*)b_gp, out);
}

// Round 16
// 211.915 us; speedup vs baseline: 1.2230x; 1.2230x over previous
//
#include <hip/hip_runtime.h>
#include <math.h>

#define NG   16
#define HID  256
#define TPTS 2048                    // table intervals; TPTS+1 entries in d_ws
#define GRID3 2048                   // token_sweep blocks (8192 waves)

typedef float f32x4 __attribute__((ext_vector_type(4)));

constexpr size_t BT      = 32ull * 2048ull;            // 65536 rows
constexpr size_t TOK_OFF = BT * HID;
constexpr size_t WT_OFF  = TOK_OFF + BT * NG * HID;
constexpr size_t NCHUNK  = BT * NG;                    // 1,048,576 1KB chunks
constexpr float  ZLO = -10.0f, ZHI = 10.0f;
constexpr float  ZSTEP  = (ZHI - ZLO) / TPTS;
constexpr float  ZSCALE = TPTS / (ZHI - ZLO);

__device__ __forceinline__ float rln(float v, int l) {  // const-lane -> SGPR
    return __int_as_float(__builtin_amdgcn_readlane(__float_as_int(v), l));
}

// ---- kernel 1: tabulate F(z) = sum_h tanh(z*w_gp[h]+b_gp[h])*w_sp[h] + b_sp
__global__ __launch_bounds__(256) void build_table(
    const float* __restrict__ w_gp, const float* __restrict__ b_gp,
    const float* __restrict__ w_sp, const float* __restrict__ b_sp,
    float* __restrict__ tbl)
{
    const int i = blockIdx.x;              // 0..TPTS
    const int h = threadIdx.x;
    const float z = ZLO + (float)i * ZSTEP;
    float v = tanhf(fmaf(z, w_gp[h], b_gp[h])) * w_sp[h];
    v += __shfl_xor(v, 1, 64);
    v += __shfl_xor(v, 2, 64);
    v += __shfl_xor(v, 4, 64);
    v += __shfl_xor(v, 8, 64);
    v += __shfl_xor(v, 16, 64);
    v += __shfl_xor(v, 32, 64);
    __shared__ float sred[4];
    if ((h & 63) == 0) sred[h >> 6] = v;
    __syncthreads();
    if (h == 0) tbl[i] = sred[0] + sred[1] + sred[2] + sred[3] + b_sp[0];
}

// ---- kernel 2: gv + scores + softmax + visit + weights (~95 MB traffic) ----
// wave = 4 rows; lane = (row j = lane>>4, group g = lane&15)
__global__ __launch_bounds__(256) void compute_kernel(
    const float*  __restrict__ x,      // (BT,64)
    const f32x4*  __restrict__ w_gp4,  // (64) float4
    const f32x4*  __restrict__ b_gp4,
    const float*  __restrict__ tbl,    // (TPTS+1)
    float* __restrict__ gvbuf,         // (BT*NG) out: group means
    float* __restrict__ out)
{
    const int lane = threadIdx.x & 63;
    const int wv   = threadIdx.x >> 6;
    const size_t row0 = ((size_t)blockIdx.x * 4 + wv) * 4;  // 4 rows per wave

    __shared__ float sx[4][4][68];     // per-wave staging (+pad, 16B-aligned)
    {
        const f32x4 xl = ((const f32x4*)x)[row0 * 16 + lane];
        const int r = lane >> 4, c = lane & 15;
        *(f32x4*)&sx[wv][r][c * 4] = xl;       // intra-wave only: no barrier
    }

    const int j   = lane >> 4;         // row within wave
    const int g   = lane & 15;         // group
    const int sub = g & 3;             // segment sizes [1,3,5,7] tiled x4
    const int sz  = 2 * sub + 1;
    const int beg = ((g >> 2) << 4) + sub * sub;   // {0,1,4,9}+16*chunk

    float s = 0.0f;
    #pragma unroll
    for (int i = 0; i < 7; ++i)
        if (i < sz) s += sx[wv][j][beg + i];
    const float gv = s * __builtin_amdgcn_rcpf((float)sz);

    // gv out (plain store; stays L2/L3-resident for the sweep's re-read)
    gvbuf[row0 * NG + lane] = gv;

    // ---- score via table lookup + lerp ----
    float idxf = fminf(fmaxf((gv - ZLO) * ZSCALE, 0.0f), (float)TPTS - 0.001f);
    const int   i0 = (int)idxf;
    const float fr = idxf - (float)i0;
    const float t0 = tbl[i0], t1 = tbl[i0 + 1];
    const float score = fmaf(fr, t1 - t0, t0);

    // ---- softmax across the 16-lane group ----
    float m = score;
    m = fmaxf(m, __shfl_xor(m, 1, 64));
    m = fmaxf(m, __shfl_xor(m, 2, 64));
    m = fmaxf(m, __shfl_xor(m, 4, 64));
    m = fmaxf(m, __shfl_xor(m, 8, 64));
    const float e = __expf(score - m);
    float ssum = e;
    ssum += __shfl_xor(ssum, 1, 64);
    ssum += __shfl_xor(ssum, 2, 64);
    ssum += __shfl_xor(ssum, 4, 64);
    ssum += __shfl_xor(ssum, 8, 64);
    const float w = e / ssum;          // weight for (row j, group g)

    __builtin_nontemporal_store(w, out + WT_OFF + row0 * NG + lane);

    // ---- dot_j = sum_g wt_g*gv_g ; visit = dot*w_gp + b_gp (exact) ----
    float d = w * gv;
    d += __shfl_xor(d, 1, 64);
    d += __shfl_xor(d, 2, 64);
    d += __shfl_xor(d, 4, 64);
    d += __shfl_xor(d, 8, 64);

    const f32x4 wg = w_gp4[lane];
    const f32x4 bg = b_gp4[lane];
    #pragma unroll
    for (int jj = 0; jj < 4; ++jj) {
        const float dj = rln(d, jj * 16);
        f32x4 vis;
        vis.x = fmaf(dj, wg.x, bg.x);
        vis.y = fmaf(dj, wg.y, bg.y);
        vis.z = fmaf(dj, wg.z, bg.z);
        vis.w = fmaf(dj, wg.w, bg.w);
        __builtin_nontemporal_store(vis,
            (f32x4*)(out + (row0 + jj) * HID + 4 * lane));
    }
}

// ---- kernel 3: fill-shaped token sweep. Grid-stride, wave-chunk = one
// (row,g) 1 KB NT store; consecutive waves -> consecutive addresses -> dense
// ~8 MB device-wide front advancing in lockstep. NT is load-bearing (R10:
// plain -18%). One outstanding store per wave with per-iter scalar prefetch
// (R11/R13/R15: any deeper/wider per-wave store pipeline regresses 13-23%).
__global__ __launch_bounds__(256) void token_sweep(
    const float*  __restrict__ gvbuf,  // (BT*NG)
    const f32x4*  __restrict__ w_gp4,
    const f32x4*  __restrict__ b_gp4,
    float* __restrict__ out)
{
    const int lane = threadIdx.x & 63;
    const int wv   = threadIdx.x >> 6;
    const f32x4 wg = w_gp4[lane];
    const f32x4 bg = b_gp4[lane];
    constexpr size_t NW    = (size_t)GRID3 * 4;          // 8192 waves
    constexpr int    NITER = (int)(NCHUNK / NW);         // 128 (exact)

    size_t c = (size_t)blockIdx.x * 4 + wv;
    float* __restrict__ tok = out + TOK_OFF + 4 * lane;

    float v = gvbuf[c];                // broadcast load, L2/L3-resident
    #pragma unroll 1
    for (int it = 0; it < NITER; ++it) {
        float nxt = 0.0f;
        if (it + 1 < NITER) nxt = gvbuf[c + NW];   // issue next load early
        f32x4 t;
        t.x = fmaf(v, wg.x, bg.x);
        t.y = fmaf(v, wg.y, bg.y);
        t.z = fmaf(v, wg.z, bg.z);
        t.w = fmaf(v, wg.w, bg.w);
        __builtin_nontemporal_store(t, (f32x4*)(tok + c * HID));
        v = nxt;
        c += NW;
    }
}

extern "C" void kernel_launch(void* const* d_in, const int* in_sizes, int n_in,
                              void* d_out, int out_size, void* d_ws, size_t ws_size,
                              hipStream_t stream) {
    (void)in_sizes; (void)n_in; (void)out_size; (void)ws_size;
    const float* x    = (const float*)d_in[0];
    const float* w_gp = (const float*)d_in[1];
    const float* b_gp = (const float*)d_in[2];
    const float* w_sp = (const float*)d_in[3];
    const float* b_sp = (const float*)d_in[4];
    float* out = (float*)d_out;
    float* tbl   = (float*)d_ws;                          // 8196 B
    float* gvbuf = (float*)((char*)d_ws + 16384);         // 4 MB (proven in R9)

    build_table<<<dim3(TPTS + 1), dim3(256), 0, stream>>>(
        w_gp, b_gp, w_sp, b_sp, tbl);

    compute_kernel<<<dim3((unsigned)(BT / 16)), dim3(256), 0, stream>>>(
        x, (const f32x4*)w_gp, (const f32x4*)b_gp, tbl, gvbuf, out);

    token_sweep<<<dim3(GRID3), dim3(256), 0, stream>>>(
        gvbuf, (const f32x4*)w_gp, (const f32x4*)b_gp, out);
}